// Round 10
// baseline (3315.660 us; speedup 1.0000x reference)
//
#include <hip/hip_runtime.h>
#include <math.h>

#define B_    32
#define S_    512
#define EMB_  512
#define HID_  1024
#define LAB_  64
#define M_    (B_ * S_)

// ---------------------------------------------------------------------------
// R19: fused pipeline, handshake hidden under passB. R18 post-mortem: round
// = 13.6k cyc, of which ~4k compute; the h0(r-1) blocking poll sat naked on
// the critical path (grace = round tail only). R19 reorders the round:
//
//   round r: [poll h1(r-3) (1+ round grace, ~instant)]
//            [ISSUE h0(r-1) poll loads, no waitcnt]
//            lgkm-barrier
//            passB: h1(r-2) = tanh(Wih1 h0(r-2) + Whh1 h1(r-3) + b)
//                   -> global write + publish (earlier than R18!)
//            vmcnt(0) + sched_barrier(0)  [rule #18: stop reg-read hoisting]
//            epoch-check landed loads; rare-miss spin; stage h0(r-1)
//            lgkm-barrier
//            passA: h0(r) = tanh(xp0(r) + Whh0 h0(r-1)) -> publish
//
// The h0 poll loads fly during passB (~2.5k cyc) => visibility+detect of
// the producer's mid-round-(r-1) publish is hidden. RAW __syncthreads()
// would emit s_waitcnt vmcnt(0) at the barrier and kill the overlap -> use
// raw "s_waitcnt lgkmcnt(0); s_barrier" (these barriers only need to order
// LDS staging vs reads; publishes need no barrier ordering).
//
// Deadlock-free (unchanged induction): publishes at round u depend only on
// data from rounds < u. Skew<=1 round: a WG staging round w needs h0(w-1)
// from every member, so nobody runs >=2 rounds ahead of a waiter => slot
// (depth 4) stale content is exactly 4 steps old = opposite epoch.
//
// LDS planes (h0 triple, h1 double; 80 KB total, 1 WG/CU):
//  sA=h0 plane[r%3] staged between bar1(r),bar2(r); read by passA(r) after
//  bar2(r) and as sP by passB(r+1) after bar1(r+1); next overwrite is at
//  round r+3 after bar1(r+3) -- all readers are >=2 collective barriers
//  earlier. s1=h1 plane[3+(r&1)] staged before bar1(r), read by passB(r)
//  before bar2(r); overwritten at round r+2 before bar1(r+2), i.e. after
//  the writer's bar2(r+1) >= collective bar2(r) > reader's passB(r). Safe.
//
// Exchange (epoch-bit, depth-4 slots, u64 = {enc(h[b0,n]), enc(h[b1,n])},
// enc = bits | epoch<<30; tanh => bit30 always 0):
//   h0(u): publish passA(u) -> slot u&3, epoch (u>>2)&1, consumed round u+1.
//   h1(u): publish passB(u+2) -> slot u&3, epoch (u>>2)&1, consumed u+3.
//   First poll of every address expects epoch 0 => uniform NANPAT fill.
// ---------------------------------------------------------------------------
#define SLOT_U64   2048                   // per (layer,slot,group)
#define LS_STRIDE  (8 * SLOT_U64)         // per (layer,slot)
#define EX_TOTAL   (2 * 4 * LS_STRIDE)    // 131072 u64 = 1 MB
#define EPBIT      0x40000000u
#define NANPAT64   0x7FC000007FC00000ULL  // epoch-1-looking fill
#define PAYMASK    0xBFFFFFFFu

typedef unsigned int u32x4 __attribute__((ext_vector_type(4)));

__device__ __forceinline__ void astore64(unsigned long long* p, unsigned long long v) {
    __hip_atomic_store(p, v, __ATOMIC_RELAXED, __HIP_MEMORY_SCOPE_AGENT);
}
// blocking: two 16B agent-scope polls, one RT
__device__ __forceinline__ void apoll2(const unsigned long long* q0,
                                       const unsigned long long* q1,
                                       u32x4& w0, u32x4& w1) {
    asm volatile(
        "global_load_dwordx4 %0, %2, off sc1\n\t"
        "global_load_dwordx4 %1, %3, off sc1\n\t"
        "s_waitcnt vmcnt(0)"
        : "=&v"(w0), "=&v"(w1)
        : "v"(q0), "v"(q1)
        : "memory");
}
// non-blocking issue: loads fly while compute proceeds
__device__ __forceinline__ void apoll2_issue(const unsigned long long* q0,
                                             const unsigned long long* q1,
                                             u32x4& w0, u32x4& w1) {
    asm volatile(
        "global_load_dwordx4 %0, %2, off sc1\n\t"
        "global_load_dwordx4 %1, %3, off sc1"
        : "=&v"(w0), "=&v"(w1)
        : "v"(q0), "v"(q1)
        : "memory");
}
__device__ __forceinline__ void vm_wait() {
    asm volatile("s_waitcnt vmcnt(0)" ::: "memory");
    __builtin_amdgcn_sched_barrier(0);   // rule #18: pin reg reads after wait
}
// barrier that does NOT drain vmcnt (keeps issued polls in flight)
__device__ __forceinline__ void lds_barrier() {
    asm volatile("s_waitcnt lgkmcnt(0)\n\ts_barrier" ::: "memory");
}
__device__ __forceinline__ bool epok4(u32x4 v, unsigned eb) {
    return ((((v[0] ^ eb) | (v[1] ^ eb)) | ((v[2] ^ eb) | (v[3] ^ eb)))
            & EPBIT) == 0;
}
// 16-acc halving-tree: after masks 1,2,4,8 + 16,32, lane p holds out(p&15).
__device__ __forceinline__ float fold16(float* v, int kg) {
#pragma unroll
    for (int st = 0; st < 4; ++st) {
        const int m  = 1 << st;
        const int nh = 8 >> st;
        const bool hi = (kg & m) != 0;
#pragma unroll
        for (int j = 0; j < 8; ++j) {
            if (j < nh) {
                const float a0 = v[2*j], a1 = v[2*j+1];
                const float got = __shfl_xor(hi ? a0 : a1, m, 64);
                v[j] = (hi ? a1 : a0) + got;
            }
        }
    }
    float r = v[0];
    r += __shfl_xor(r, 16, 64);
    r += __shfl_xor(r, 32, 64);
    return r;
}

// ---------------------------------------------------------------------------
// fp32 tiled GEMM (unchanged): BM=128, BN=64, BK=16, 256 thr, 8x4/thread.
// ---------------------------------------------------------------------------
__global__ __launch_bounds__(256) void gemm_bias(
    const float* __restrict__ A, const int* __restrict__ tokens,
    const float* __restrict__ W, const float* __restrict__ bias,
    const float* __restrict__ bias2, float* __restrict__ C,
    int M, int K, int N)
{
    __shared__ float As[128][17];
    __shared__ float Ws[64][17];

    const int tid = threadIdx.x;
    const int tx  = tid & 15;
    const int ty  = tid >> 4;
    const int n0  = blockIdx.x * 64;
    const int m0  = blockIdx.y * 128;

    const int lr  = tid >> 2;
    const int lk  = (tid & 3) << 2;

    const int ar0 = tokens ? tokens[m0 + lr]      : (m0 + lr);
    const int ar1 = tokens ? tokens[m0 + 64 + lr] : (m0 + 64 + lr);
    const float* __restrict__ arow0 = A + (size_t)ar0 * K;
    const float* __restrict__ arow1 = A + (size_t)ar1 * K;
    const float* __restrict__ wrow  = W + (size_t)(n0 + lr) * K;

    float bs[4];
#pragma unroll
    for (int j = 0; j < 4; ++j) {
        int n = n0 + tx * 4 + j;
        bs[j] = bias[n] + (bias2 ? bias2[n] : 0.0f);
    }

    float acc[8][4] = {};

    for (int k0 = 0; k0 < K; k0 += 16) {
        const float4 a0 = *(const float4*)(arow0 + k0 + lk);
        const float4 a1 = *(const float4*)(arow1 + k0 + lk);
        const float4 wv = *(const float4*)(wrow  + k0 + lk);
        __syncthreads();
        As[lr][lk + 0] = a0.x; As[lr][lk + 1] = a0.y;
        As[lr][lk + 2] = a0.z; As[lr][lk + 3] = a0.w;
        As[64 + lr][lk + 0] = a1.x; As[64 + lr][lk + 1] = a1.y;
        As[64 + lr][lk + 2] = a1.z; As[64 + lr][lk + 3] = a1.w;
        Ws[lr][lk + 0] = wv.x; Ws[lr][lk + 1] = wv.y;
        Ws[lr][lk + 2] = wv.z; Ws[lr][lk + 3] = wv.w;
        __syncthreads();

#pragma unroll
        for (int kk = 0; kk < 16; ++kk) {
            float b[4], a[8];
#pragma unroll
            for (int j = 0; j < 4; ++j) b[j] = Ws[tx * 4 + j][kk];
#pragma unroll
            for (int i = 0; i < 8; ++i) a[i] = As[ty * 8 + i][kk];
#pragma unroll
            for (int i = 0; i < 8; ++i)
#pragma unroll
                for (int j = 0; j < 4; ++j)
                    acc[i][j] += a[i] * b[j];
        }
    }

#pragma unroll
    for (int i = 0; i < 8; ++i) {
        const int m = m0 + ty * 8 + i;
        float4 v;
        v.x = acc[i][0] + bs[0];
        v.y = acc[i][1] + bs[1];
        v.z = acc[i][2] + bs[2];
        v.w = acc[i][3] + bs[3];
        *(float4*)(C + (size_t)m * N + n0 + tx * 4) = v;
    }
}

// ---------------------------------------------------------------------------
// Fill: NANPAT everywhere; every first poll expects epoch 0.
// ---------------------------------------------------------------------------
__global__ __launch_bounds__(256) void fill_poison(unsigned long long* p, int n)
{
    const int i = blockIdx.x * 256 + threadIdx.x;
    if (i < n) p[i] = NANPAT64;
}

// ---------------------------------------------------------------------------
// Fused 2-layer scan, passB-first round order. Weights: 3 x (4n x 16q) =
// 192 regs. Partition: slice s = wg>>3 (32 neurons), group g = wg&7
// (4 batches). Rounds r = 0..513.
// ---------------------------------------------------------------------------
__global__ __launch_bounds__(512, 2) void rnn_fused(
    const float* __restrict__ Whh0, const float* __restrict__ Whh1,
    const float* __restrict__ Wih1, const float* __restrict__ b_ih1,
    const float* __restrict__ b_hh1, float* __restrict__ xb,
    unsigned long long* __restrict__ ex)
{
    extern __shared__ float smem[];
    float2* hb = (float2*)smem;        // h0: planes 0..2; h1: planes 3..4

    const int wg  = blockIdx.x;
    const int g   = wg & 7;            // group: batches g*4..g*4+3
    const int s   = wg >> 3;           // slice: neurons s*32..s*32+31
    const int tid = threadIdx.x;       // 0..511
    const int j8  = tid >> 6;          // wave: neurons s*32 + j8*4 ..+3
    const int kg  = tid & 63;          // lane; k = kg + 64q
    const int b0  = g * 4;

    // weights: 4 neurons x 16 strided k, three matrices (lane-coalesced)
    float w0[4][16], wx[4][16], wh[4][16];
    {
        const size_t base = (size_t)(s * 32 + j8 * 4) * HID_ + kg;
#pragma unroll
        for (int i = 0; i < 4; ++i)
#pragma unroll
            for (int q = 0; q < 16; ++q) {
                const size_t o = base + (size_t)i * HID_ + (size_t)q * 64;
                w0[i][q] = Whh0[o];
                wx[i][q] = Wih1[o];
                wh[i][q] = Whh1[o];
            }
    }

    const int i4 = (kg >> 2) & 3;      // output neuron (lanes<16)
    const int bb = kg & 3;             // output batch  (lanes<16)
    const int ok = s * 32 + j8 * 4 + i4;
    float bsum = 0.f;
    if (kg < 16) bsum = b_ih1[ok] + b_hh1[ok];

    float* px0 = xb + ((size_t)(b0 + bb) * S_) * HID_ + ok;  // xp0 read (b,r)
    float* px1 = px0;                             // h1 write (b, r-2)

    unsigned long long* const exg = ex + (size_t)g * SLOT_U64;
    // consumer 16B lines: neurons tid and 512+tid (words 2n, 2n+1)
    const int c0 = 2 * tid, c1 = 1024 + 2 * tid;

    for (int r = 0; r <= S_ + 1; ++r) {
        // ---- xp0 prefetch (rides until passA) ----
        float xpv = 0.f;
        if (kg < 16 && r < S_) xpv = *px0;
        px0 += HID_;

        float2* sA = hb + (size_t)(r % 3) * 2048;        // h0(r-1) stage
        float2* sP = hb + (size_t)((r + 2) % 3) * 2048;  // h0(r-2) (passB)
        float2* s1 = hb + (size_t)(3 + (r & 1)) * 2048;  // h1(r-3) stage

        const unsigned eb0 = ((((unsigned)(r - 1)) >> 2) & 1u) << 30;
        const unsigned eb1 = ((((unsigned)(r - 3)) >> 2) & 1u) << 30;
        const unsigned long long* pl0 =
            exg + (size_t)((r - 1) & 3) * LS_STRIDE;
        const unsigned long long* pl1 =
            exg + (size_t)(4 + ((r - 3) & 3)) * LS_STRIDE;

        // ---- phase 0: zero-fills + blocking h1(r-3) poll ----
        if (r == 0) {
#pragma unroll
            for (int k = 0; k < 4; ++k)
                sA[tid + 512 * k] = make_float2(0.f, 0.f);
        }
        if (r == 2) {
#pragma unroll
            for (int k = 0; k < 4; ++k)
                s1[tid + 512 * k] = make_float2(0.f, 0.f);
        }
        if (r >= 3) {
            unsigned pend = 3u;
            u32x4 w0v, w1v;
            do {
                apoll2(pl1 + c0, pl1 + c1, w0v, w1v);
                if ((pend & 1u) && epok4(w0v, eb1)) {
                    s1[tid]        = make_float2(
                        __uint_as_float(w0v[0] & PAYMASK),
                        __uint_as_float(w0v[1] & PAYMASK));
                    s1[1024 + tid] = make_float2(
                        __uint_as_float(w0v[2] & PAYMASK),
                        __uint_as_float(w0v[3] & PAYMASK));
                    pend &= ~1u;
                }
                if ((pend & 2u) && epok4(w1v, eb1)) {
                    s1[512 + tid]  = make_float2(
                        __uint_as_float(w1v[0] & PAYMASK),
                        __uint_as_float(w1v[1] & PAYMASK));
                    s1[1536 + tid] = make_float2(
                        __uint_as_float(w1v[2] & PAYMASK),
                        __uint_as_float(w1v[3] & PAYMASK));
                    pend &= ~2u;
                }
            } while (pend);
        }

        // ---- issue h0(r-1) polls; they fly across the barrier + passB ----
        u32x4 pa0, pa1;
        const bool needh0 = (r >= 1 && r <= S_);
        if (needh0) apoll2_issue(pl0 + c0, pl0 + c1, pa0, pa1);

        lds_barrier();   // bar1: s1 staged; vmcnt NOT drained

        // ---- pass B: h1(r-2) = tanh(Wih1 h0(r-2) + Whh1 h1(r-3) + b) ----
        if (r >= 2) {
            float v[16] = {};
#pragma unroll
            for (int q = 0; q < 16; ++q) {
                const float2 a0 = sP[q * 64 + kg];          // h0(r-2)
                const float2 a1 = sP[1024 + q * 64 + kg];
                const float2 c0f = s1[q * 64 + kg];         // h1(r-3)
                const float2 c1f = s1[1024 + q * 64 + kg];
#pragma unroll
                for (int i = 0; i < 4; ++i) {
                    const float fb = wx[i][q];
                    v[i*4+0] += fb * a0.x; v[i*4+1] += fb * a0.y;
                    v[i*4+2] += fb * a1.x; v[i*4+3] += fb * a1.y;
                    const float fc = wh[i][q];
                    v[i*4+0] += fc * c0f.x; v[i*4+1] += fc * c0f.y;
                    v[i*4+2] += fc * c1f.x; v[i*4+3] += fc * c1f.y;
                }
            }
            const float r1 = fold16(v, kg);
            float h1 = 0.f;
            if (kg < 16) h1 = tanhf(r1 + bsum);
            const float h1p = __shfl_xor(h1, 1, 64);
            if (kg < 16) *px1 = h1;     // h1(r-2) overwrites consumed xp0
            if (kg < 16 && (bb & 1) == 0) {
                const unsigned pe = (((unsigned)(r - 2) >> 2) & 1u) << 30;
                const unsigned long long u =
                    ((unsigned long long)(__float_as_uint(h1p) | pe) << 32) |
                    (unsigned long long)(__float_as_uint(h1) | pe);
                astore64(exg + (size_t)(4 + ((r - 2) & 3)) * LS_STRIDE
                             + 2 * ok + (bb >> 1), u);
            }
            px1 += HID_;
        }

        // ---- h0(r-1): check landed loads, rare-miss spin, stage ----
        if (needh0) {
            vm_wait();     // vmcnt(0) + sched_barrier(0)
            unsigned pend = 3u;
            if (epok4(pa0, eb0)) {
                sA[tid]        = make_float2(
                    __uint_as_float(pa0[0] & PAYMASK),
                    __uint_as_float(pa0[1] & PAYMASK));
                sA[1024 + tid] = make_float2(
                    __uint_as_float(pa0[2] & PAYMASK),
                    __uint_as_float(pa0[3] & PAYMASK));
                pend &= ~1u;
            }
            if (epok4(pa1, eb0)) {
                sA[512 + tid]  = make_float2(
                    __uint_as_float(pa1[0] & PAYMASK),
                    __uint_as_float(pa1[1] & PAYMASK));
                sA[1536 + tid] = make_float2(
                    __uint_as_float(pa1[2] & PAYMASK),
                    __uint_as_float(pa1[3] & PAYMASK));
                pend &= ~2u;
            }
            while (pend) {
                u32x4 w0v, w1v;
                apoll2(pl0 + c0, pl0 + c1, w0v, w1v);
                if ((pend & 1u) && epok4(w0v, eb0)) {
                    sA[tid]        = make_float2(
                        __uint_as_float(w0v[0] & PAYMASK),
                        __uint_as_float(w0v[1] & PAYMASK));
                    sA[1024 + tid] = make_float2(
                        __uint_as_float(w0v[2] & PAYMASK),
                        __uint_as_float(w0v[3] & PAYMASK));
                    pend &= ~1u;
                }
                if ((pend & 2u) && epok4(w1v, eb0)) {
                    sA[512 + tid]  = make_float2(
                        __uint_as_float(w1v[0] & PAYMASK),
                        __uint_as_float(w1v[1] & PAYMASK));
                    sA[1536 + tid] = make_float2(
                        __uint_as_float(w1v[2] & PAYMASK),
                        __uint_as_float(w1v[3] & PAYMASK));
                    pend &= ~2u;
                }
            }
        }

        lds_barrier();   // bar2: sA staged -> passA may read

        // ---- pass A: h0(r) = tanh(xp0(r) + Whh0 h0(r-1)); publish ----
        if (r < S_) {
            float v[16] = {};
#pragma unroll
            for (int q = 0; q < 16; ++q) {
                const float2 a0 = sA[q * 64 + kg];          // batches 0,1
                const float2 a1 = sA[1024 + q * 64 + kg];   // batches 2,3
#pragma unroll
                for (int i = 0; i < 4; ++i) {
                    const float fa = w0[i][q];
                    v[i*4+0] += fa * a0.x; v[i*4+1] += fa * a0.y;
                    v[i*4+2] += fa * a1.x; v[i*4+3] += fa * a1.y;
                }
            }
            const float r0 = fold16(v, kg);
            float h0 = 0.f;
            if (kg < 16) h0 = tanhf(xpv + r0);
            const float h0p = __shfl_xor(h0, 1, 64);   // partner batch
            if (kg < 16 && (bb & 1) == 0) {
                const unsigned pe = (((unsigned)r >> 2) & 1u) << 30;
                const unsigned long long u =
                    ((unsigned long long)(__float_as_uint(h0p) | pe) << 32) |
                    (unsigned long long)(__float_as_uint(h0) | pe);
                astore64(exg + (size_t)(r & 3) * LS_STRIDE
                             + 2 * ok + (bb >> 1), u);
            }
        }
        // no trailing barrier: plane rotation proves no WAR (see header)
    }
}

extern "C" void kernel_launch(void* const* d_in, const int* in_sizes, int n_in,
                              void* d_out, int out_size, void* d_ws, size_t ws_size,
                              hipStream_t stream)
{
    const int*   tokens = (const int*)  d_in[0];
    const float* emb    = (const float*)d_in[1];
    const float* W_ih0  = (const float*)d_in[2];
    const float* W_hh0  = (const float*)d_in[3];
    const float* b_ih0  = (const float*)d_in[4];
    const float* b_hh0  = (const float*)d_in[5];
    const float* W_ih1  = (const float*)d_in[6];
    const float* W_hh1  = (const float*)d_in[7];
    const float* b_ih1  = (const float*)d_in[8];
    const float* b_hh1  = (const float*)d_in[9];
    const float* W_out  = (const float*)d_in[10];
    const float* b_out  = (const float*)d_in[11];
    float* out = (float*)d_out;

    float* buf = (float*)d_ws;                            // 64 MiB: xp0 -> h1
    unsigned long long* ex = (unsigned long long*)d_out;  // 1 MB exchange

    // 96 KB dynamic LDS -> exactly 1 WG/CU (256 WGs co-resident on 256 CUs)
    const size_t scan_lds = 98304;
    hipFuncSetAttribute((const void*)rnn_fused,
                        hipFuncAttributeMaxDynamicSharedMemorySize, (int)scan_lds);

    // 1) xp0 = gather(emb,tokens) @ W_ih0^T + b_ih0 + b_hh0  -> buf
    gemm_bias<<<dim3(HID_ / 64, M_ / 128), 256, 0, stream>>>(
        emb, tokens, W_ih0, b_ih0, b_hh0, buf, M_, EMB_, HID_);

    // 2) pre-fill exchange epochs
    fill_poison<<<EX_TOTAL / 256, 256, 0, stream>>>(ex, EX_TOTAL);

    // 3) fused 2-layer skewed scan: xp0 consumed, h1 left in buf
    rnn_fused<<<256, 512, scan_lds, stream>>>(
        W_hh0, W_hh1, W_ih1, b_ih1, b_hh1, buf, ex);

    // 4) out = h1 @ W_out^T + b_out (fully rewrites d_out incl. ex region)
    gemm_bias<<<dim3(LAB_ / 64, M_ / 128), 256, 0, stream>>>(
        buf, nullptr, W_out, b_out, nullptr, out, M_, HID_, LAB_);
}